// Round 1
// 159.409 us; speedup vs baseline: 1.0264x; 1.0264x over previous
//
#include <hip/hip_runtime.h>

#define B_  256
#define T_  256
#define S_  20
#define U1  32
#define G1  128   // 4*U1
#define U2  24
#define G2  96    // 4*U2
#define NT  16    // 16-row t-tiles per sequence

typedef __attribute__((ext_vector_type(8))) short short8;   // 8 bf16 = 4 VGPRs
typedef __attribute__((ext_vector_type(4))) float f32x4;    // MFMA acc
typedef __attribute__((ext_vector_type(2))) float f32x2;    // pk_fma pair

// Raw-HW activations (v_exp_f32 = 2^x, pre-scaled by log2e). R7: 134->74us.
__device__ __forceinline__ float sigmoidf_(float x) {
    return __builtin_amdgcn_rcpf(1.0f + __builtin_amdgcn_exp2f(x * -1.44269504f));
}
__device__ __forceinline__ float tanhf_fast(float x) {   // 1 - 2/(1+e^{2x})
    return 1.0f - 2.0f * __builtin_amdgcn_rcpf(1.0f + __builtin_amdgcn_exp2f(x * 2.88539008f));
}
// quad_perm [1,0,3,2]: lane ^= 1 swap, pure-VALU (replaces ds_bpermute on the
// phase-2 critical chain; cross-32 shuffle no longer needed with pair layout)
__device__ __forceinline__ float dpp_xor1(float x) {
    return __int_as_float(__builtin_amdgcn_update_dpp(
        0, __float_as_int(x), 0xB1, 0xF, 0xF, true));
}

__device__ __forceinline__ unsigned short f2bf(float a) {
    unsigned int u = __float_as_uint(a);
    u += 0x7FFFu + ((u >> 16) & 1u);
    return (unsigned short)(u >> 16);
}
__device__ __forceinline__ unsigned int pack2bf(float a, float b) {
    unsigned int ua = __float_as_uint(a); ua += 0x7FFFu + ((ua >> 16) & 1u);
    unsigned int ub = __float_as_uint(b); ub += 0x7FFFu + ((ub >> 16) & 1u);
    return (ua >> 16) | (ub & 0xFFFF0000u);
}
union frag_u { short8 v; unsigned int u[4]; };
union h2x  { unsigned int u32; _Float16 h[2]; };

// FUSED producer-consumer kernel: 1 block/sequence, 512 threads (8 waves).
// Producers (all waves): MFMA inner LSTM per 16-row tile; P tile -> LDS f16
//   in UNIT-MAJOR pair layout [t][u][4 gates]; per-tile flag released after.
// Consumer (wave 0, after producing tile 0 only): outer recurrence reading
//   P from LDS. R13: pair-lane gate layout (lane 2u: i,f | lane 2u+1: g,o)
//   -> cross-gate exchange is a quad_perm DPP (VALU) instead of 2 ds_bpermute;
//   matvec as f32x2 v_pk_fma (24 pk ops vs 48 fmac). s_setprio(2) on waves
//   0-3 during their first tile shrinks the consumer's tile-1 stall.
__global__ __attribute__((amdgpu_flat_work_group_size(512, 512)))
__attribute__((amdgpu_waves_per_eu(2, 2)))
void fused_kernel(
    const float* __restrict__ x,        // [B*T*S]
    const int*   __restrict__ lengths,  // [B]
    const float* __restrict__ Wi,       // [G1]
    const float* __restrict__ Ui,       // [U1*G1]
    const float* __restrict__ bi,       // [G1]
    const float* __restrict__ Wo,       // [U1*G2]
    const float* __restrict__ Uo,       // [U2*G2]
    const float* __restrict__ bo,       // [G2]
    const float* __restrict__ Wd,       // [U2]
    const float* __restrict__ bd,       // [1]
    float* __restrict__ out)            // [B]
{
    __shared__ __align__(16) _Float16      Pl[T_][G2];      // [t][u*4+g], 48 KB
    __shared__ __align__(16) unsigned short hbb[8][16][40]; // per-wave h tiles
    __shared__ unsigned int flags[NT];
    const int b    = blockIdx.x;
    const int len  = lengths[b];                 // >= 1
    const int tid  = threadIdx.x;
    const int w    = __builtin_amdgcn_readfirstlane(tid >> 6);   // wave 0..7
    const int lane = tid & 63;
    const int q    = lane >> 4;
    const int n    = lane & 15;

    if (tid < NT) flags[tid] = 0;
    __syncthreads();                             // only barrier: flag init

    // priority: waves 0-3 produce tiles 0-3 (the consumer's first needs) at
    // prio 2; dropped after first tile (wave0 -> 1 = consumer wins vs tails).
    if (w <= 3) __builtin_amdgcn_s_setprio(2);

    // ---- one-time fragment/bias loads (all waves produce) ----
    frag_u Bui[8];
#pragma unroll
    for (int tt = 0; tt < 8; ++tt)
#pragma unroll
        for (int k2 = 0; k2 < 4; ++k2)
            Bui[tt].u[k2] = pack2bf(Ui[(8 * q + 2 * k2) * G1 + 16 * tt + n],
                                    Ui[(8 * q + 2 * k2 + 1) * G1 + 16 * tt + n]);
    frag_u Bwo[6];
#pragma unroll
    for (int tt = 0; tt < 6; ++tt)
#pragma unroll
        for (int k2 = 0; k2 < 4; ++k2)
            Bwo[tt].u[k2] = pack2bf(Wo[(8 * q + 2 * k2) * G2 + 16 * tt + n],
                                    Wo[(8 * q + 2 * k2 + 1) * G2 + 16 * tt + n]);
    float bi_l[8], Wi_l[8], bo_l[6];
#pragma unroll
    for (int tt = 0; tt < 8; ++tt) { bi_l[tt] = bi[16 * tt + n]; Wi_l[tt] = Wi[16 * tt + n]; }
#pragma unroll
    for (int tt = 0; tt < 6; ++tt) bo_l[tt] = bo[16 * tt + n];
    // P-store targets: col=16tt+n -> (g=col/24, u=col%24) -> offset u*4+g
    int pcol[6];
#pragma unroll
    for (int tt = 0; tt < 6; ++tt) {
        const int col = 16 * tt + n;
        const int g = col / 24;
        pcol[tt] = (col - 24 * g) * 4 + g;
    }

    // ---- tile worklist: wave0 gets only tile 0 (starts consuming ASAP);
    //      wave1 gets {1,8,9} so early tiles land first; others {w, w+8}.
    int tl[3]; int ntl;
    if (w == 0)      { tl[0] = 0; tl[1] = 0; tl[2] = 0; ntl = 1; }
    else if (w == 1) { tl[0] = 1; tl[1] = 8; tl[2] = 9; ntl = 3; }
    else             { tl[0] = w; tl[1] = w + 8; tl[2] = 0; ntl = 2; }

#pragma unroll 1
    for (int i = 0; i < ntl; ++i) {
        const int tile = tl[i];
        const int wt0  = tile * 16;
        if (wt0 >= len) break;                   // lists increasing: later also masked

        const float* xr = x + (size_t)(b * T_ + wt0 + 4 * q) * S_;
        float c[2][4];
#pragma unroll
        for (int uh = 0; uh < 2; ++uh)
#pragma unroll
            for (int r = 0; r < 4; ++r) c[uh][r] = 0.0f;

        float xc[4];
#pragma unroll
        for (int r = 0; r < 4; ++r) xc[r] = xr[r * S_];

        // peeled s = 0 (h == 0: no MFMA)
        {
            f32x4 acc[8];
#pragma unroll
            for (int tt = 0; tt < 8; ++tt)
#pragma unroll
                for (int r = 0; r < 4; ++r)
                    acc[tt][r] = bi_l[tt] + xc[r] * Wi_l[tt];
#pragma unroll
            for (int uh = 0; uh < 2; ++uh)
#pragma unroll
                for (int r = 0; r < 4; ++r) {
                    const float iv = sigmoidf_(acc[0 + uh][r]);
                    const float fv = sigmoidf_(acc[2 + uh][r]);
                    const float gv = tanhf_fast(acc[4 + uh][r]);
                    const float ov = sigmoidf_(acc[6 + uh][r]);
                    c[uh][r] = fv * c[uh][r] + iv * gv;
                    hbb[w][4 * q + r][n + 16 * uh] = f2bf(ov * tanhf_fast(c[uh][r]));
                }
        }
#pragma unroll
        for (int r = 0; r < 4; ++r) xc[r] = xr[r * S_ + 1];

        // steady state s = 1..19
#pragma unroll 1
        for (int s = 1; s < S_; ++s) {
            const int sn = (s + 1 < S_) ? s + 1 : S_ - 1;
            float xnx[4];
#pragma unroll
            for (int r = 0; r < 4; ++r) xnx[r] = xr[r * S_ + sn];

            f32x4 acc[8];
#pragma unroll
            for (int tt = 0; tt < 8; ++tt)
#pragma unroll
                for (int r = 0; r < 4; ++r)
                    acc[tt][r] = bi_l[tt] + xc[r] * Wi_l[tt];

            const short8 A = *(const short8*)&hbb[w][n][8 * q];
#pragma unroll
            for (int tt = 0; tt < 8; ++tt)
                acc[tt] = __builtin_amdgcn_mfma_f32_16x16x32_bf16(A, Bui[tt].v, acc[tt], 0, 0, 0);

#pragma unroll
            for (int uh = 0; uh < 2; ++uh)
#pragma unroll
                for (int r = 0; r < 4; ++r) {
                    const float iv = sigmoidf_(acc[0 + uh][r]);
                    const float fv = sigmoidf_(acc[2 + uh][r]);
                    const float gv = tanhf_fast(acc[4 + uh][r]);
                    const float ov = sigmoidf_(acc[6 + uh][r]);
                    c[uh][r] = fv * c[uh][r] + iv * gv;
                    hbb[w][4 * q + r][n + 16 * uh] = f2bf(ov * tanhf_fast(c[uh][r]));
                }
#pragma unroll
            for (int r = 0; r < 4; ++r) xc[r] = xnx[r];
        }

        // P tile = bo + h @ Wo -> LDS, unit-major pair layout
        {
            const short8 A = *(const short8*)&hbb[w][n][8 * q];
            f32x4 accp[6];
#pragma unroll
            for (int tt = 0; tt < 6; ++tt) {
#pragma unroll
                for (int r = 0; r < 4; ++r) accp[tt][r] = bo_l[tt];
                accp[tt] = __builtin_amdgcn_mfma_f32_16x16x32_bf16(A, Bwo[tt].v, accp[tt], 0, 0, 0);
            }
#pragma unroll
            for (int r = 0; r < 4; ++r) {
                const int tr = wt0 + 4 * q + r;
#pragma unroll
                for (int tt = 0; tt < 6; ++tt)
                    Pl[tr][pcol[tt]] = (_Float16)accp[tt][r];
            }
        }
        // release this tile to the consumer (DS ops in-order; release fences)
        __hip_atomic_store(&flags[tile], 1u, __ATOMIC_RELEASE, __HIP_MEMORY_SCOPE_WORKGROUP);
        if (i == 0) {
            if (w == 0) __builtin_amdgcn_s_setprio(1);   // consumer priority
            else        __builtin_amdgcn_s_setprio(0);   // back to baseline
        }
    }

    if (w != 0) return;                          // producers retire

    // ================= phase 2: outer LSTM + head (wave 0) =================
    // Pair-lane layout: lane 2u computes gates (i,f), lane 2u+1 gates (g,o)
    // of unit u. Cross-gate exchange = quad_perm xor-1 DPP (no DS on chain).
    const int p = lane & 1;                      // 0: i,f  1: g,o
    const int u = (lane < 2 * U2) ? (lane >> 1) : (U2 - 1);
    const int cA = p ? (2 * U2 + u) : u;         // col of zA dot
    const int cB = p ? (3 * U2 + u) : (U2 + u);  // col of zB dot

    f32x2 w2_[U2];                               // 48 weight VGPRs (pk pairs)
#pragma unroll
    for (int k = 0; k < U2; ++k) {
        w2_[k].x = Uo[k * G2 + cA];
        w2_[k].y = Uo[k * G2 + cB];
    }

    // one ds_read_b64 per row; keep only this lane's gate pair (1 cndmask+2 cvt)
    auto ldrow2 = [&](int t) -> f32x2 {
        const uint2 raw = *reinterpret_cast<const uint2*>(&Pl[t][4 * u]);
        h2x s_; s_.u32 = p ? raw.y : raw.x;      // even: (i,f)  odd: (g,o)
        f32x2 r; r.x = (float)s_.h[0]; r.y = (float)s_.h[1];
        return r;
    };

    float cu = 0.0f, hu;
    {   // peeled t = 0 (h == 0, c == 0): z = P row 0
        const f32x2 z0 = ldrow2(0);
        const float zA = z0.x, zB = z0.y;
        const float swA = dpp_xor1(zA);
        const float swB = dpp_xor1(zB);
        const float z_i = p ? swA : zA;
        const float z_f = p ? swB : zB;
        const float z_g = p ? zA : swA;
        const float z_o = p ? zB : swB;
        const float ig = sigmoidf_(z_i);
        const float fg = sigmoidf_(z_f);
        const float gg = tanhf_fast(z_g);
        const float og = sigmoidf_(z_o);
        cu = fg * cu + ig * gg;
        hu = og * tanhf_fast(cu);
    }
    int wtile = 0;
    f32x2 nxt = ldrow2((1 < len) ? 1 : 0);       // prefetch row for t=1

#pragma unroll 1
    for (int t = 1; t < len; ++t) {
        // prefetch row t+1 (clamped); spin only when crossing into a new tile
        const int tn = (t + 1 < len) ? (t + 1) : (len - 1);
        const int ttile = tn >> 4;
        if (ttile != wtile) {                    // wave-uniform
            while (__hip_atomic_load(&flags[ttile], __ATOMIC_ACQUIRE,
                                     __HIP_MEMORY_SCOPE_WORKGROUP) == 0u)
                __builtin_amdgcn_s_sleep(1);
            wtile = ttile;
        }
        const f32x2 pf = ldrow2(tn);

        // batch the h broadcast (unit k lives on lane 2k; independent readlanes)
        float hk[U2];
#pragma unroll
        for (int k = 0; k < U2; ++k)
            hk[k] = __int_as_float(__builtin_amdgcn_readlane(__float_as_int(hu), 2 * k));

        // matvec as v_pk_fma_f32: 4 chains x depth 6 (same order as scalar ver)
        f32x2 ab0 = nxt;
        f32x2 ab1 = {0.0f, 0.0f}, ab2 = {0.0f, 0.0f}, ab3 = {0.0f, 0.0f};
#pragma unroll
        for (int k = 0; k < U2; k += 4) {
            ab0 += w2_[k]     * hk[k];
            ab1 += w2_[k + 1] * hk[k + 1];
            ab2 += w2_[k + 2] * hk[k + 2];
            ab3 += w2_[k + 3] * hk[k + 3];
        }
        const f32x2 zz = (ab0 + ab1) + (ab2 + ab3);
        const float zA = zz.x, zB = zz.y;

        const float swA = dpp_xor1(zA);
        const float swB = dpp_xor1(zB);
        const float z_i = p ? swA : zA;
        const float z_f = p ? swB : zB;
        const float z_g = p ? zA : swA;
        const float z_o = p ? zB : swB;

        const float ig = sigmoidf_(z_i);
        const float fg = sigmoidf_(z_f);
        const float gg = tanhf_fast(z_g);
        const float og = sigmoidf_(z_o);
        cu = fg * cu + ig * gg;
        hu = og * tanhf_fast(cu);                // identical on both parities

        nxt = pf;
    }

    // dense sigmoid head
    float acc = bd[0];
#pragma unroll
    for (int k = 0; k < U2; ++k)
        acc += __int_as_float(__builtin_amdgcn_readlane(__float_as_int(hu), 2 * k)) * Wd[k];
    if (lane == 0) out[b] = sigmoidf_(acc);
}

extern "C" void kernel_launch(void* const* d_in, const int* in_sizes, int n_in,
                              void* d_out, int out_size, void* d_ws, size_t ws_size,
                              hipStream_t stream) {
    const float* x       = (const float*)d_in[0];
    const int*   lengths = (const int*)  d_in[1];
    const float* Wi      = (const float*)d_in[2];
    const float* Ui      = (const float*)d_in[3];
    const float* bi      = (const float*)d_in[4];
    const float* Wo      = (const float*)d_in[5];
    const float* Uo      = (const float*)d_in[6];
    const float* bo      = (const float*)d_in[7];
    const float* Wd      = (const float*)d_in[8];
    const float* bd      = (const float*)d_in[9];
    float* out = (float*)d_out;

    fused_kernel<<<dim3(B_), dim3(512), 0, stream>>>(
        x, lengths, Wi, Ui, bi, Wo, Uo, bo, Wd, bd, out);
}

// Round 2
// 149.358 us; speedup vs baseline: 1.0954x; 1.0673x over previous
//
#include <hip/hip_runtime.h>

#define B_  256
#define T_  256
#define S_  20
#define U1  32
#define G1  128   // 4*U1
#define U2  24
#define G2  96    // 4*U2
#define NT  16    // 16-row t-tiles per sequence

typedef __attribute__((ext_vector_type(8))) short short8;   // 8 bf16 = 4 VGPRs
typedef __attribute__((ext_vector_type(4))) float f32x4;    // MFMA acc
typedef __attribute__((ext_vector_type(2))) float f32x2;    // pk pair

#define KSIG  (-1.44269504f)   // -log2(e)
#define KTANH ( 2.88539008f)   // 2*log2(e)

// Raw-HW activations (v_exp_f32 = 2^x, pre-scaled by log2e). R7: 134->74us.
__device__ __forceinline__ float sigmoidf_(float x) {
    return __builtin_amdgcn_rcpf(1.0f + __builtin_amdgcn_exp2f(x * KSIG));
}
__device__ __forceinline__ float tanhf_fast(float x) {   // 1 - 2/(1+e^{2x})
    return 1.0f - 2.0f * __builtin_amdgcn_rcpf(1.0f + __builtin_amdgcn_exp2f(x * KTANH));
}
// quad_perm [1,0,3,2]: lane ^= 1 swap, pure-VALU
__device__ __forceinline__ float dpp_xor1(float x) {
    return __int_as_float(__builtin_amdgcn_update_dpp(
        0, __float_as_int(x), 0xB1, 0xF, 0xF, true));
}
// d = 1 + exp2(k*z), componentwise exp2 (trans is scalar-only; mul/add pack)
__device__ __forceinline__ f32x2 dexp2(f32x2 z, float k) {
    f32x2 t = z * k;
    f32x2 e;
    e.x = __builtin_amdgcn_exp2f(t.x);
    e.y = __builtin_amdgcn_exp2f(t.y);
    return e + 1.0f;
}
// elementwise recip of 4 independent denoms with 2 rcp + 3 pk_mul (vs 4 rcp):
// R = rcp(d01*d23); 1/d01 = R*d23; 1/d23 = R*d01.  Trans issue 32->22 cy.
__device__ __forceinline__ void brcp4(f32x2 d01, f32x2 d23, f32x2& s01, f32x2& s23) {
    const f32x2 m = d01 * d23;
    f32x2 R;
    R.x = __builtin_amdgcn_rcpf(m.x);
    R.y = __builtin_amdgcn_rcpf(m.y);
    s01 = R * d23;
    s23 = R * d01;
}

__device__ __forceinline__ unsigned short f2bf(float a) {
    unsigned int u = __float_as_uint(a);
    u += 0x7FFFu + ((u >> 16) & 1u);
    return (unsigned short)(u >> 16);
}
__device__ __forceinline__ unsigned int pack2bf(float a, float b) {
    unsigned int ua = __float_as_uint(a); ua += 0x7FFFu + ((ua >> 16) & 1u);
    unsigned int ub = __float_as_uint(b); ub += 0x7FFFu + ((ub >> 16) & 1u);
    return (ua >> 16) | (ub & 0xFFFF0000u);
}
union frag_u { short8 v; unsigned int u[4]; };
union h2x  { unsigned int u32; _Float16 h[2]; };

// FUSED producer-consumer kernel: 1 block/sequence, 512 threads (8 waves).
// R14 theory: phase 1 is ISSUE-bound, dominated by 1/4-rate trans ops
// (MfmaUtil arithmetic => effective clock ~1.2 GHz; 640 of ~1100 issue-cy
// per tile-step are exp2/rcp). Changes:
//  * producer: batched reciprocals (brcp4: 4 denoms -> 2 rcp + 3 pk_mul)
//    and f32x2 packed gate math over row-pairs (acc comps are adjacent).
//  * consumer: per-parity gate pipeline -- even lanes hold (z_i,z_f), odd
//    (z_g,z_o) pre-exchange, so ONE pk pipeline with per-lane constants
//    computes all four activations across the parity pair (10 -> 6 trans
//    per step); h moves to odd lanes (readlane 2k+1).
__global__ __attribute__((amdgpu_flat_work_group_size(512, 512)))
__attribute__((amdgpu_waves_per_eu(2, 2)))
void fused_kernel(
    const float* __restrict__ x,        // [B*T*S]
    const int*   __restrict__ lengths,  // [B]
    const float* __restrict__ Wi,       // [G1]
    const float* __restrict__ Ui,       // [U1*G1]
    const float* __restrict__ bi,       // [G1]
    const float* __restrict__ Wo,       // [U1*G2]
    const float* __restrict__ Uo,       // [U2*G2]
    const float* __restrict__ bo,       // [G2]
    const float* __restrict__ Wd,       // [U2]
    const float* __restrict__ bd,       // [1]
    float* __restrict__ out)            // [B]
{
    __shared__ __align__(16) _Float16      Pl[T_][G2];      // [t][u*4+g], 48 KB
    __shared__ __align__(16) unsigned short hbb[8][16][40]; // per-wave h tiles
    __shared__ unsigned int flags[NT];
    const int b    = blockIdx.x;
    const int len  = lengths[b];                 // >= 1
    const int tid  = threadIdx.x;
    const int w    = __builtin_amdgcn_readfirstlane(tid >> 6);   // wave 0..7
    const int lane = tid & 63;
    const int q    = lane >> 4;
    const int n    = lane & 15;

    if (tid < NT) flags[tid] = 0;
    __syncthreads();                             // only barrier: flag init

    // priority: waves 0-3 produce tiles 0-3 (the consumer's first needs) at
    // prio 2; dropped after first tile (wave0 -> 1 = consumer wins vs tails).
    if (w <= 3) __builtin_amdgcn_s_setprio(2);

    // ---- one-time fragment/bias loads (all waves produce) ----
    frag_u Bui[8];
#pragma unroll
    for (int tt = 0; tt < 8; ++tt)
#pragma unroll
        for (int k2 = 0; k2 < 4; ++k2)
            Bui[tt].u[k2] = pack2bf(Ui[(8 * q + 2 * k2) * G1 + 16 * tt + n],
                                    Ui[(8 * q + 2 * k2 + 1) * G1 + 16 * tt + n]);
    frag_u Bwo[6];
#pragma unroll
    for (int tt = 0; tt < 6; ++tt)
#pragma unroll
        for (int k2 = 0; k2 < 4; ++k2)
            Bwo[tt].u[k2] = pack2bf(Wo[(8 * q + 2 * k2) * G2 + 16 * tt + n],
                                    Wo[(8 * q + 2 * k2 + 1) * G2 + 16 * tt + n]);
    float bi_l[8], Wi_l[8], bo_l[6];
#pragma unroll
    for (int tt = 0; tt < 8; ++tt) { bi_l[tt] = bi[16 * tt + n]; Wi_l[tt] = Wi[16 * tt + n]; }
#pragma unroll
    for (int tt = 0; tt < 6; ++tt) bo_l[tt] = bo[16 * tt + n];
    // P-store targets: col=16tt+n -> (g=col/24, u=col%24) -> offset u*4+g
    int pcol[6];
#pragma unroll
    for (int tt = 0; tt < 6; ++tt) {
        const int col = 16 * tt + n;
        const int g = col / 24;
        pcol[tt] = (col - 24 * g) * 4 + g;
    }

    // ---- tile worklist: wave0 gets only tile 0 (starts consuming ASAP);
    //      wave1 gets {1,8,9} so early tiles land first; others {w, w+8}.
    int tl[3]; int ntl;
    if (w == 0)      { tl[0] = 0; tl[1] = 0; tl[2] = 0; ntl = 1; }
    else if (w == 1) { tl[0] = 1; tl[1] = 8; tl[2] = 9; ntl = 3; }
    else             { tl[0] = w; tl[1] = w + 8; tl[2] = 0; ntl = 2; }

#pragma unroll 1
    for (int i = 0; i < ntl; ++i) {
        const int tile = tl[i];
        const int wt0  = tile * 16;
        if (wt0 >= len) break;                   // lists increasing: later also masked

        const float* xr = x + (size_t)(b * T_ + wt0 + 4 * q) * S_;
        // cell state as row-pair packs: c01 = rows (4q+0,4q+1), c23 = (+2,+3)
        f32x2 c01[2], c23[2];
#pragma unroll
        for (int uh = 0; uh < 2; ++uh) { c01[uh] = {0.0f, 0.0f}; c23[uh] = {0.0f, 0.0f}; }

        // packed activation block: 60 trans ops/step (was 80), pk elsewhere
        auto activate = [&](f32x4* acc) {
#pragma unroll
            for (int uh = 0; uh < 2; ++uh) {
                const f32x2 zi01 = { acc[0 + uh][0], acc[0 + uh][1] };
                const f32x2 zi23 = { acc[0 + uh][2], acc[0 + uh][3] };
                const f32x2 zf01 = { acc[2 + uh][0], acc[2 + uh][1] };
                const f32x2 zf23 = { acc[2 + uh][2], acc[2 + uh][3] };
                const f32x2 zg01 = { acc[4 + uh][0], acc[4 + uh][1] };
                const f32x2 zg23 = { acc[4 + uh][2], acc[4 + uh][3] };
                const f32x2 zo01 = { acc[6 + uh][0], acc[6 + uh][1] };
                const f32x2 zo23 = { acc[6 + uh][2], acc[6 + uh][3] };

                f32x2 si01, si23, sf01, sf23, rg01, rg23, so01, so23;
                brcp4(dexp2(zi01, KSIG),  dexp2(zi23, KSIG),  si01, si23);
                brcp4(dexp2(zf01, KSIG),  dexp2(zf23, KSIG),  sf01, sf23);
                brcp4(dexp2(zg01, KTANH), dexp2(zg23, KTANH), rg01, rg23);
                brcp4(dexp2(zo01, KSIG),  dexp2(zo23, KSIG),  so01, so23);
                const f32x2 g01 = 1.0f - 2.0f * rg01;
                const f32x2 g23 = 1.0f - 2.0f * rg23;
                c01[uh] = sf01 * c01[uh] + si01 * g01;
                c23[uh] = sf23 * c23[uh] + si23 * g23;
                f32x2 rc01, rc23;
                brcp4(dexp2(c01[uh], KTANH), dexp2(c23[uh], KTANH), rc01, rc23);
                const f32x2 t01 = 1.0f - 2.0f * rc01;
                const f32x2 t23 = 1.0f - 2.0f * rc23;
                const f32x2 h01 = so01 * t01;
                const f32x2 h23 = so23 * t23;
                hbb[w][4 * q + 0][n + 16 * uh] = f2bf(h01.x);
                hbb[w][4 * q + 1][n + 16 * uh] = f2bf(h01.y);
                hbb[w][4 * q + 2][n + 16 * uh] = f2bf(h23.x);
                hbb[w][4 * q + 3][n + 16 * uh] = f2bf(h23.y);
            }
        };

        float xc[4];
#pragma unroll
        for (int r = 0; r < 4; ++r) xc[r] = xr[r * S_];

        // peeled s = 0 (h == 0: no MFMA)
        {
            f32x4 acc[8];
#pragma unroll
            for (int tt = 0; tt < 8; ++tt)
#pragma unroll
                for (int r = 0; r < 4; ++r)
                    acc[tt][r] = bi_l[tt] + xc[r] * Wi_l[tt];
            activate(acc);
        }
#pragma unroll
        for (int r = 0; r < 4; ++r) xc[r] = xr[r * S_ + 1];

        // steady state s = 1..19
#pragma unroll 1
        for (int s = 1; s < S_; ++s) {
            const int sn = (s + 1 < S_) ? s + 1 : S_ - 1;
            float xnx[4];
#pragma unroll
            for (int r = 0; r < 4; ++r) xnx[r] = xr[r * S_ + sn];

            f32x4 acc[8];
#pragma unroll
            for (int tt = 0; tt < 8; ++tt)
#pragma unroll
                for (int r = 0; r < 4; ++r)
                    acc[tt][r] = bi_l[tt] + xc[r] * Wi_l[tt];

            const short8 A = *(const short8*)&hbb[w][n][8 * q];
#pragma unroll
            for (int tt = 0; tt < 8; ++tt)
                acc[tt] = __builtin_amdgcn_mfma_f32_16x16x32_bf16(A, Bui[tt].v, acc[tt], 0, 0, 0);

            activate(acc);
#pragma unroll
            for (int r = 0; r < 4; ++r) xc[r] = xnx[r];
        }

        // P tile = bo + h @ Wo -> LDS, unit-major pair layout
        {
            const short8 A = *(const short8*)&hbb[w][n][8 * q];
            f32x4 accp[6];
#pragma unroll
            for (int tt = 0; tt < 6; ++tt) {
#pragma unroll
                for (int r = 0; r < 4; ++r) accp[tt][r] = bo_l[tt];
                accp[tt] = __builtin_amdgcn_mfma_f32_16x16x32_bf16(A, Bwo[tt].v, accp[tt], 0, 0, 0);
            }
#pragma unroll
            for (int r = 0; r < 4; ++r) {
                const int tr = wt0 + 4 * q + r;
#pragma unroll
                for (int tt = 0; tt < 6; ++tt)
                    Pl[tr][pcol[tt]] = (_Float16)accp[tt][r];
            }
        }
        // release this tile to the consumer (DS ops in-order; release fences)
        __hip_atomic_store(&flags[tile], 1u, __ATOMIC_RELEASE, __HIP_MEMORY_SCOPE_WORKGROUP);
        if (i == 0) {
            if (w == 0) __builtin_amdgcn_s_setprio(1);   // consumer priority
            else        __builtin_amdgcn_s_setprio(0);   // back to baseline
        }
    }

    if (w != 0) return;                          // producers retire

    // ================= phase 2: outer LSTM + head (wave 0) =================
    // Parity pipeline: even lane 2u holds (z_i,z_f), odd lane 2u+1 (z_g,z_o).
    // No z-swap: per-lane constants make one pk pipeline compute sigma on even
    // and (tanh,sigma) on odd. c lives on even lanes, h on odd lanes.
    const int p = lane & 1;                      // 0: i,f  1: g,o
    const int u = (lane < 2 * U2) ? (lane >> 1) : (U2 - 1);
    const int cA = p ? (2 * U2 + u) : u;         // col of zA dot
    const int cB = p ? (3 * U2 + u) : (U2 + u);  // col of zB dot

    const f32x2 kAB = { p ? KTANH : KSIG, KSIG };         // pre-scale
    const f32x2 mAB = { p ? -2.0f : 1.0f, 1.0f };         // finish mul
    const f32x2 aAB = { p ?  1.0f : 0.0f, 0.0f };         // finish add

    // even: (sig_i, sig_f) ; odd: (tanh_g, sig_o) -- 2 exp2 + 2 rcp total
    auto gates2 = [&](f32x2 z) -> f32x2 {
        const f32x2 t = z * kAB;
        f32x2 e;
        e.x = __builtin_amdgcn_exp2f(t.x);
        e.y = __builtin_amdgcn_exp2f(t.y);
        const f32x2 d = e + 1.0f;
        f32x2 r;
        r.x = __builtin_amdgcn_rcpf(d.x);
        r.y = __builtin_amdgcn_rcpf(d.y);
        return r * mAB + aAB;
    };

    f32x2 w2_[U2];                               // 48 weight VGPRs (pk pairs)
#pragma unroll
    for (int k = 0; k < U2; ++k) {
        w2_[k].x = Uo[k * G2 + cA];
        w2_[k].y = Uo[k * G2 + cB];
    }

    // one ds_read_b64 per row; keep only this lane's gate pair (1 cndmask+2 cvt)
    auto ldrow2 = [&](int t) -> f32x2 {
        const uint2 raw = *reinterpret_cast<const uint2*>(&Pl[t][4 * u]);
        h2x s_; s_.u32 = p ? raw.y : raw.x;      // even: (i,f)  odd: (g,o)
        f32x2 r; r.x = (float)s_.h[0]; r.y = (float)s_.h[1];
        return r;
    };

    float cu = 0.0f, hu;                         // cu valid on even, hu on odd
    {   // peeled t = 0 (h == 0, c == 0): z = P row 0
        const f32x2 out2 = gates2(ldrow2(0));
        const float tg  = dpp_xor1(out2.x);      // even <- odd's tanh_g
        cu = out2.x * tg;                        // even: sig_i * tanh_g
        const float tc  = tanhf_fast(cu);        // valid on even
        const float tcs = dpp_xor1(tc);          // odd <- even's tanh(c)
        hu = out2.y * tcs;                       // odd: sig_o * tanh(c)
    }
    int wtile = 0;
    f32x2 nxt = ldrow2((1 < len) ? 1 : 0);       // prefetch row for t=1

#pragma unroll 1
    for (int t = 1; t < len; ++t) {
        // prefetch row t+1 (clamped); spin only when crossing into a new tile
        const int tn = (t + 1 < len) ? (t + 1) : (len - 1);
        const int ttile = tn >> 4;
        if (ttile != wtile) {                    // wave-uniform
            while (__hip_atomic_load(&flags[ttile], __ATOMIC_ACQUIRE,
                                     __HIP_MEMORY_SCOPE_WORKGROUP) == 0u)
                __builtin_amdgcn_s_sleep(1);
            wtile = ttile;
        }
        const f32x2 pf = ldrow2(tn);

        // batch the h broadcast (unit k's h lives on lane 2k+1)
        float hk[U2];
#pragma unroll
        for (int k = 0; k < U2; ++k)
            hk[k] = __int_as_float(__builtin_amdgcn_readlane(__float_as_int(hu), 2 * k + 1));

        // matvec as v_pk_fma_f32: 4 chains x depth 6
        f32x2 ab0 = nxt;
        f32x2 ab1 = {0.0f, 0.0f}, ab2 = {0.0f, 0.0f}, ab3 = {0.0f, 0.0f};
#pragma unroll
        for (int k = 0; k < U2; k += 4) {
            ab0 += w2_[k]     * hk[k];
            ab1 += w2_[k + 1] * hk[k + 1];
            ab2 += w2_[k + 2] * hk[k + 2];
            ab3 += w2_[k + 3] * hk[k + 3];
        }
        const f32x2 zz = (ab0 + ab1) + (ab2 + ab3);

        const f32x2 out2 = gates2(zz);           // even:(si,sf) odd:(tg,so)
        const float tg  = dpp_xor1(out2.x);      // even <- tanh_g
        cu = out2.y * cu + out2.x * tg;          // even: sf*c + si*tg
        const float tc  = tanhf_fast(cu);        // even
        const float tcs = dpp_xor1(tc);          // odd <- tanh(c)
        hu = out2.y * tcs;                       // odd: so*tanh(c)

        nxt = pf;
    }

    // dense sigmoid head (h on odd lanes)
    float acc = bd[0];
#pragma unroll
    for (int k = 0; k < U2; ++k)
        acc += __int_as_float(__builtin_amdgcn_readlane(__float_as_int(hu), 2 * k + 1)) * Wd[k];
    if (lane == 0) out[b] = sigmoidf_(acc);
}

extern "C" void kernel_launch(void* const* d_in, const int* in_sizes, int n_in,
                              void* d_out, int out_size, void* d_ws, size_t ws_size,
                              hipStream_t stream) {
    const float* x       = (const float*)d_in[0];
    const int*   lengths = (const int*)  d_in[1];
    const float* Wi      = (const float*)d_in[2];
    const float* Ui      = (const float*)d_in[3];
    const float* bi      = (const float*)d_in[4];
    const float* Wo      = (const float*)d_in[5];
    const float* Uo      = (const float*)d_in[6];
    const float* bo      = (const float*)d_in[7];
    const float* Wd      = (const float*)d_in[8];
    const float* bd      = (const float*)d_in[9];
    float* out = (float*)d_out;

    fused_kernel<<<dim3(B_), dim3(512), 0, stream>>>(
        x, lengths, Wi, Ui, bi, Wo, Uo, bo, Wd, bd, out);
}

// Round 3
// 149.310 us; speedup vs baseline: 1.0958x; 1.0003x over previous
//
#include <hip/hip_runtime.h>

#define B_  256
#define T_  256
#define S_  20
#define U1  32
#define G1  128   // 4*U1
#define U2  24
#define G2  96    // 4*U2
#define NT  16    // 16-row t-tiles per sequence

typedef __attribute__((ext_vector_type(8))) short short8;   // 8 bf16 = 4 VGPRs
typedef __attribute__((ext_vector_type(4))) float f32x4;    // MFMA acc
typedef __attribute__((ext_vector_type(2))) float f32x2;    // pk pair

#define KSIG  (-1.44269504f)   // -log2(e)
#define KTANH ( 2.88539008f)   // 2*log2(e)

// Raw-HW activations (v_exp_f32 = 2^x, pre-scaled by log2e). R7: 134->74us.
__device__ __forceinline__ float sigmoidf_(float x) {
    return __builtin_amdgcn_rcpf(1.0f + __builtin_amdgcn_exp2f(x * KSIG));
}
__device__ __forceinline__ float tanhf_fast(float x) {   // 1 - 2/(1+e^{2x})
    return 1.0f - 2.0f * __builtin_amdgcn_rcpf(1.0f + __builtin_amdgcn_exp2f(x * KTANH));
}
// quad_perm [1,0,3,2]: lane ^= 1 swap, pure-VALU
__device__ __forceinline__ float dpp_xor1(float x) {
    return __int_as_float(__builtin_amdgcn_update_dpp(
        0, __float_as_int(x), 0xB1, 0xF, 0xF, true));
}
// d = 1 + exp2(k*z), componentwise exp2 (trans is scalar-only; mul/add pack)
__device__ __forceinline__ f32x2 dexp2(f32x2 z, float k) {
    f32x2 t = z * k;
    f32x2 e;
    e.x = __builtin_amdgcn_exp2f(t.x);
    e.y = __builtin_amdgcn_exp2f(t.y);
    return e + 1.0f;
}
// elementwise recip of 4 independent denoms with 2 rcp + 3 pk_mul (vs 4 rcp)
__device__ __forceinline__ void brcp4(f32x2 d01, f32x2 d23, f32x2& s01, f32x2& s23) {
    const f32x2 m = d01 * d23;
    f32x2 R;
    R.x = __builtin_amdgcn_rcpf(m.x);
    R.y = __builtin_amdgcn_rcpf(m.y);
    s01 = R * d23;
    s23 = R * d01;
}

__device__ __forceinline__ unsigned short f2bf(float a) {
    unsigned int u = __float_as_uint(a);
    u += 0x7FFFu + ((u >> 16) & 1u);
    return (unsigned short)(u >> 16);
}
__device__ __forceinline__ unsigned int pack2bf(float a, float b) {
    unsigned int ua = __float_as_uint(a); ua += 0x7FFFu + ((ua >> 16) & 1u);
    unsigned int ub = __float_as_uint(b); ub += 0x7FFFu + ((ub >> 16) & 1u);
    return (ua >> 16) | (ub & 0xFFFF0000u);
}
union frag_u { short8 v; unsigned int u[4]; };
union h2x  { unsigned int u32; _Float16 h[2]; };

// FUSED producer-consumer kernel: 1 block/sequence, 512 threads (8 waves).
// R15 theory: phase 2 spans the whole kernel (~800 cy/step vs ~270 modeled);
// the per-step ds_read_b64 P-row prefetch puts ~120cy LDS latency on the
// recurrence chain every step (compiler emits lgkmcnt(0) at first use).
// Fix: TILE-BATCHED row registers -- 16x ds_read_b32 per tile (parity offset
// folded into the address), double-buffered; the next tile's reads are
// issued mid-tile so their latency hides under ~8 steps of compute. The
// 16-step runs are then DS-free. Static buffer naming via macros (no
// runtime-indexed local arrays -> no scratch).
__global__ __attribute__((amdgpu_flat_work_group_size(512, 512)))
__attribute__((amdgpu_waves_per_eu(2, 2)))
void fused_kernel(
    const float* __restrict__ x,        // [B*T*S]
    const int*   __restrict__ lengths,  // [B]
    const float* __restrict__ Wi,       // [G1]
    const float* __restrict__ Ui,       // [U1*G1]
    const float* __restrict__ bi,       // [G1]
    const float* __restrict__ Wo,       // [U1*G2]
    const float* __restrict__ Uo,       // [U2*G2]
    const float* __restrict__ bo,       // [G2]
    const float* __restrict__ Wd,       // [U2]
    const float* __restrict__ bd,       // [1]
    float* __restrict__ out)            // [B]
{
    __shared__ __align__(16) _Float16      Pl[T_][G2];      // [t][u*4+g], 48 KB
    __shared__ __align__(16) unsigned short hbb[8][16][40]; // per-wave h tiles
    __shared__ unsigned int flags[NT];
    const int b    = blockIdx.x;
    const int len  = lengths[b];                 // >= 1
    const int tid  = threadIdx.x;
    const int w    = __builtin_amdgcn_readfirstlane(tid >> 6);   // wave 0..7
    const int lane = tid & 63;
    const int q    = lane >> 4;
    const int n    = lane & 15;

    if (tid < NT) flags[tid] = 0;
    __syncthreads();                             // only barrier: flag init

    // priority: waves 0-3 produce tiles 0-3 (the consumer's first needs) at
    // prio 2; dropped after first tile (wave0 -> 1 = consumer wins vs tails).
    if (w <= 3) __builtin_amdgcn_s_setprio(2);

    // ---- one-time fragment/bias loads (all waves produce) ----
    frag_u Bui[8];
#pragma unroll
    for (int tt = 0; tt < 8; ++tt)
#pragma unroll
        for (int k2 = 0; k2 < 4; ++k2)
            Bui[tt].u[k2] = pack2bf(Ui[(8 * q + 2 * k2) * G1 + 16 * tt + n],
                                    Ui[(8 * q + 2 * k2 + 1) * G1 + 16 * tt + n]);
    frag_u Bwo[6];
#pragma unroll
    for (int tt = 0; tt < 6; ++tt)
#pragma unroll
        for (int k2 = 0; k2 < 4; ++k2)
            Bwo[tt].u[k2] = pack2bf(Wo[(8 * q + 2 * k2) * G2 + 16 * tt + n],
                                    Wo[(8 * q + 2 * k2 + 1) * G2 + 16 * tt + n]);
    float bi_l[8], Wi_l[8], bo_l[6];
#pragma unroll
    for (int tt = 0; tt < 8; ++tt) { bi_l[tt] = bi[16 * tt + n]; Wi_l[tt] = Wi[16 * tt + n]; }
#pragma unroll
    for (int tt = 0; tt < 6; ++tt) bo_l[tt] = bo[16 * tt + n];
    // P-store targets: col=16tt+n -> (g=col/24, u=col%24) -> offset u*4+g
    int pcol[6];
#pragma unroll
    for (int tt = 0; tt < 6; ++tt) {
        const int col = 16 * tt + n;
        const int g = col / 24;
        pcol[tt] = (col - 24 * g) * 4 + g;
    }

    // ---- tile worklist: wave0 gets only tile 0 (starts consuming ASAP);
    //      wave1 gets {1,8,9} so early tiles land first; others {w, w+8}.
    int tl[3]; int ntl;
    if (w == 0)      { tl[0] = 0; tl[1] = 0; tl[2] = 0; ntl = 1; }
    else if (w == 1) { tl[0] = 1; tl[1] = 8; tl[2] = 9; ntl = 3; }
    else             { tl[0] = w; tl[1] = w + 8; tl[2] = 0; ntl = 2; }

#pragma unroll 1
    for (int i = 0; i < ntl; ++i) {
        const int tile = tl[i];
        const int wt0  = tile * 16;
        if (wt0 >= len) break;                   // lists increasing: later also masked

        const float* xr = x + (size_t)(b * T_ + wt0 + 4 * q) * S_;
        // cell state as row-pair packs: c01 = rows (4q+0,4q+1), c23 = (+2,+3)
        f32x2 c01[2], c23[2];
#pragma unroll
        for (int uh = 0; uh < 2; ++uh) { c01[uh] = {0.0f, 0.0f}; c23[uh] = {0.0f, 0.0f}; }

        // packed activation block: 60 trans ops/step, pk elsewhere
        auto activate = [&](f32x4* acc) {
#pragma unroll
            for (int uh = 0; uh < 2; ++uh) {
                const f32x2 zi01 = { acc[0 + uh][0], acc[0 + uh][1] };
                const f32x2 zi23 = { acc[0 + uh][2], acc[0 + uh][3] };
                const f32x2 zf01 = { acc[2 + uh][0], acc[2 + uh][1] };
                const f32x2 zf23 = { acc[2 + uh][2], acc[2 + uh][3] };
                const f32x2 zg01 = { acc[4 + uh][0], acc[4 + uh][1] };
                const f32x2 zg23 = { acc[4 + uh][2], acc[4 + uh][3] };
                const f32x2 zo01 = { acc[6 + uh][0], acc[6 + uh][1] };
                const f32x2 zo23 = { acc[6 + uh][2], acc[6 + uh][3] };

                f32x2 si01, si23, sf01, sf23, rg01, rg23, so01, so23;
                brcp4(dexp2(zi01, KSIG),  dexp2(zi23, KSIG),  si01, si23);
                brcp4(dexp2(zf01, KSIG),  dexp2(zf23, KSIG),  sf01, sf23);
                brcp4(dexp2(zg01, KTANH), dexp2(zg23, KTANH), rg01, rg23);
                brcp4(dexp2(zo01, KSIG),  dexp2(zo23, KSIG),  so01, so23);
                const f32x2 g01 = 1.0f - 2.0f * rg01;
                const f32x2 g23 = 1.0f - 2.0f * rg23;
                c01[uh] = sf01 * c01[uh] + si01 * g01;
                c23[uh] = sf23 * c23[uh] + si23 * g23;
                f32x2 rc01, rc23;
                brcp4(dexp2(c01[uh], KTANH), dexp2(c23[uh], KTANH), rc01, rc23);
                const f32x2 t01 = 1.0f - 2.0f * rc01;
                const f32x2 t23 = 1.0f - 2.0f * rc23;
                const f32x2 h01 = so01 * t01;
                const f32x2 h23 = so23 * t23;
                hbb[w][4 * q + 0][n + 16 * uh] = f2bf(h01.x);
                hbb[w][4 * q + 1][n + 16 * uh] = f2bf(h01.y);
                hbb[w][4 * q + 2][n + 16 * uh] = f2bf(h23.x);
                hbb[w][4 * q + 3][n + 16 * uh] = f2bf(h23.y);
            }
        };

        float xc[4];
#pragma unroll
        for (int r = 0; r < 4; ++r) xc[r] = xr[r * S_];

        // peeled s = 0 (h == 0: no MFMA)
        {
            f32x4 acc[8];
#pragma unroll
            for (int tt = 0; tt < 8; ++tt)
#pragma unroll
                for (int r = 0; r < 4; ++r)
                    acc[tt][r] = bi_l[tt] + xc[r] * Wi_l[tt];
            activate(acc);
        }
#pragma unroll
        for (int r = 0; r < 4; ++r) xc[r] = xr[r * S_ + 1];

        // steady state s = 1..19
#pragma unroll 1
        for (int s = 1; s < S_; ++s) {
            const int sn = (s + 1 < S_) ? s + 1 : S_ - 1;
            float xnx[4];
#pragma unroll
            for (int r = 0; r < 4; ++r) xnx[r] = xr[r * S_ + sn];

            f32x4 acc[8];
#pragma unroll
            for (int tt = 0; tt < 8; ++tt)
#pragma unroll
                for (int r = 0; r < 4; ++r)
                    acc[tt][r] = bi_l[tt] + xc[r] * Wi_l[tt];

            const short8 A = *(const short8*)&hbb[w][n][8 * q];
#pragma unroll
            for (int tt = 0; tt < 8; ++tt)
                acc[tt] = __builtin_amdgcn_mfma_f32_16x16x32_bf16(A, Bui[tt].v, acc[tt], 0, 0, 0);

            activate(acc);
#pragma unroll
            for (int r = 0; r < 4; ++r) xc[r] = xnx[r];
        }

        // P tile = bo + h @ Wo -> LDS, unit-major pair layout
        {
            const short8 A = *(const short8*)&hbb[w][n][8 * q];
            f32x4 accp[6];
#pragma unroll
            for (int tt = 0; tt < 6; ++tt) {
#pragma unroll
                for (int r = 0; r < 4; ++r) accp[tt][r] = bo_l[tt];
                accp[tt] = __builtin_amdgcn_mfma_f32_16x16x32_bf16(A, Bwo[tt].v, accp[tt], 0, 0, 0);
            }
#pragma unroll
            for (int r = 0; r < 4; ++r) {
                const int tr = wt0 + 4 * q + r;
#pragma unroll
                for (int tt = 0; tt < 6; ++tt)
                    Pl[tr][pcol[tt]] = (_Float16)accp[tt][r];
            }
        }
        // release this tile to the consumer (DS ops in-order; release fences)
        __hip_atomic_store(&flags[tile], 1u, __ATOMIC_RELEASE, __HIP_MEMORY_SCOPE_WORKGROUP);
        if (i == 0) {
            if (w == 0) __builtin_amdgcn_s_setprio(1);   // consumer priority
            else        __builtin_amdgcn_s_setprio(0);   // back to baseline
        }
    }

    if (w != 0) return;                          // producers retire

    // ================= phase 2: outer LSTM + head (wave 0) =================
    // Parity pipeline: even lane 2u holds (z_i,z_f), odd lane 2u+1 (z_g,z_o).
    // c lives on even lanes, h on odd lanes. Rows come from tile-batched
    // REGISTER buffers (DS-free steps).
    const int p = lane & 1;                      // 0: i,f  1: g,o
    const int u = (lane < 2 * U2) ? (lane >> 1) : (U2 - 1);
    const int cA = p ? (2 * U2 + u) : u;         // col of zA dot
    const int cB = p ? (3 * U2 + u) : (U2 + u);  // col of zB dot

    const f32x2 kAB = { p ? KTANH : KSIG, KSIG };         // pre-scale
    const f32x2 mAB = { p ? -2.0f : 1.0f, 1.0f };         // finish mul
    const f32x2 aAB = { p ?  1.0f : 0.0f, 0.0f };         // finish add

    // even: (sig_i, sig_f) ; odd: (tanh_g, sig_o) -- 2 exp2 + 2 rcp total
    auto gates2 = [&](f32x2 z) -> f32x2 {
        const f32x2 t = z * kAB;
        f32x2 e;
        e.x = __builtin_amdgcn_exp2f(t.x);
        e.y = __builtin_amdgcn_exp2f(t.y);
        const f32x2 d = e + 1.0f;
        f32x2 r;
        r.x = __builtin_amdgcn_rcpf(d.x);
        r.y = __builtin_amdgcn_rcpf(d.y);
        return r * mAB + aAB;
    };

    f32x2 w2_[U2];                               // 48 weight VGPRs (pk pairs)
#pragma unroll
    for (int k = 0; k < U2; ++k) {
        w2_[k].x = Uo[k * G2 + cA];
        w2_[k].y = Uo[k * G2 + cB];
    }

    // per-lane byte offset within a P row: the parity select is folded into
    // the address -> a single ds_read_b32 fetches exactly this lane's pair.
    const int rowoff = 8 * u + 4 * p;            // bytes; row stride 192 B
    const char* Pb = reinterpret_cast<const char*>(&Pl[0][0]);
    const int ntiles = (len + 15) >> 4;

    unsigned bufA[16], bufB[16];                 // double-buffered row regs

    float cu = 0.0f, hu = 0.0f;

// one recurrence step from a register-held row (identical math to R2)
#define STEP_ROW(RW) do {                                                     \
    h2x s_; s_.u32 = (RW);                                                    \
    f32x2 pr; pr.x = (float)s_.h[0]; pr.y = (float)s_.h[1];                   \
    float hk[U2];                                                             \
    _Pragma("unroll")                                                         \
    for (int kq = 0; kq < U2; ++kq)                                           \
        hk[kq] = __int_as_float(                                              \
            __builtin_amdgcn_readlane(__float_as_int(hu), 2 * kq + 1));       \
    f32x2 ab0 = pr;                                                           \
    f32x2 ab1 = {0.0f, 0.0f}, ab2 = {0.0f, 0.0f}, ab3 = {0.0f, 0.0f};         \
    _Pragma("unroll")                                                         \
    for (int kq = 0; kq < U2; kq += 4) {                                      \
        ab0 += w2_[kq]     * hk[kq];                                          \
        ab1 += w2_[kq + 1] * hk[kq + 1];                                      \
        ab2 += w2_[kq + 2] * hk[kq + 2];                                      \
        ab3 += w2_[kq + 3] * hk[kq + 3];                                      \
    }                                                                         \
    const f32x2 zz = (ab0 + ab1) + (ab2 + ab3);                               \
    const f32x2 o2 = gates2(zz);                                              \
    const float tg  = dpp_xor1(o2.x);                                         \
    cu = o2.y * cu + o2.x * tg;                                               \
    const float tc  = tanhf_fast(cu);                                         \
    const float tcs = dpp_xor1(tc);                                           \
    hu = o2.y * tcs;                                                          \
} while (0)

// consume tile K from CUR; mid-tile, spin + issue next tile's reads into NXT
// (their lgkmcnt wait lands at the next tile's first use -> latency hidden)
#define TILE_BODY(K, CUR, NXT, J0) do {                                       \
    _Pragma("unroll")                                                         \
    for (int j = (J0); j < 8; ++j) {                                          \
        if (16 * (K) + j >= len) goto p2done;                                 \
        STEP_ROW(CUR[j]);                                                     \
    }                                                                         \
    if ((K) + 1 < ntiles) {                                                   \
        while (__hip_atomic_load(&flags[(K) + 1], __ATOMIC_ACQUIRE,           \
                                 __HIP_MEMORY_SCOPE_WORKGROUP) == 0u)         \
            __builtin_amdgcn_s_sleep(1);                                      \
        _Pragma("unroll")                                                     \
        for (int j = 0; j < 16; ++j)                                          \
            NXT[j] = *reinterpret_cast<const unsigned*>(                      \
                Pb + (16 * ((K) + 1) + j) * (G2 * 2) + rowoff);               \
    }                                                                         \
    _Pragma("unroll")                                                         \
    for (int j = 8; j < 16; ++j) {                                            \
        if (16 * (K) + j >= len) goto p2done;                                 \
        STEP_ROW(CUR[j]);                                                     \
    }                                                                         \
} while (0)

    // tile 0: produced by this wave itself (own DS writes are in-order)
#pragma unroll
    for (int j = 0; j < 16; ++j)
        bufA[j] = *reinterpret_cast<const unsigned*>(Pb + j * (G2 * 2) + rowoff);

    {   // peeled t = 0 (h == 0, c == 0): z = P row 0
        h2x s_; s_.u32 = bufA[0];
        f32x2 z0; z0.x = (float)s_.h[0]; z0.y = (float)s_.h[1];
        const f32x2 o2 = gates2(z0);
        const float tg  = dpp_xor1(o2.x);        // even <- odd's tanh_g
        cu = o2.x * tg;                          // c0 = si*tg (same both par)
        const float tc  = tanhf_fast(cu);
        const float tcs = dpp_xor1(tc);
        hu = o2.y * tcs;                         // odd: so*tanh(c)
    }

    TILE_BODY(0, bufA, bufB, 1);
#pragma unroll 1
    for (int k = 1; k < ntiles; ++k) {
        if (k & 1) TILE_BODY(k, bufB, bufA, 0);
        else       TILE_BODY(k, bufA, bufB, 0);
    }
p2done: ;

    // dense sigmoid head (h on odd lanes)
    float acc = bd[0];
#pragma unroll
    for (int k = 0; k < U2; ++k)
        acc += __int_as_float(__builtin_amdgcn_readlane(__float_as_int(hu), 2 * k + 1)) * Wd[k];
    if (lane == 0) out[b] = sigmoidf_(acc);

#undef TILE_BODY
#undef STEP_ROW
}

extern "C" void kernel_launch(void* const* d_in, const int* in_sizes, int n_in,
                              void* d_out, int out_size, void* d_ws, size_t ws_size,
                              hipStream_t stream) {
    const float* x       = (const float*)d_in[0];
    const int*   lengths = (const int*)  d_in[1];
    const float* Wi      = (const float*)d_in[2];
    const float* Ui      = (const float*)d_in[3];
    const float* bi      = (const float*)d_in[4];
    const float* Wo      = (const float*)d_in[5];
    const float* Uo      = (const float*)d_in[6];
    const float* bo      = (const float*)d_in[7];
    const float* Wd      = (const float*)d_in[8];
    const float* bd      = (const float*)d_in[9];
    float* out = (float*)d_out;

    fused_kernel<<<dim3(B_), dim3(512), 0, stream>>>(
        x, lengths, Wi, Ui, bi, Wo, Uo, bo, Wd, bd, out);
}

// Round 4
// 144.629 us; speedup vs baseline: 1.1312x; 1.0324x over previous
//
#include <hip/hip_runtime.h>

#define B_  256
#define T_  256
#define S_  20
#define U1  32
#define G1  128   // 4*U1
#define U2  24
#define G2  96    // 4*U2
#define NT  16    // 16-row t-tiles per sequence

typedef __attribute__((ext_vector_type(8))) short short8;   // 8 bf16 = 4 VGPRs
typedef __attribute__((ext_vector_type(4))) float f32x4;    // MFMA acc
typedef __attribute__((ext_vector_type(2))) float f32x2;    // pk pair

#define KSIG  (-1.44269504f)   // -log2(e)
#define KTANH ( 2.88539008f)   // 2*log2(e)

// Raw-HW activations (v_exp_f32 = 2^x, pre-scaled by log2e). R7: 134->74us.
__device__ __forceinline__ float sigmoidf_(float x) {
    return __builtin_amdgcn_rcpf(1.0f + __builtin_amdgcn_exp2f(x * KSIG));
}
__device__ __forceinline__ float tanhf_fast(float x) {   // 1 - 2/(1+e^{2x})
    return 1.0f - 2.0f * __builtin_amdgcn_rcpf(1.0f + __builtin_amdgcn_exp2f(x * KTANH));
}
// quad_perm [1,0,3,2]: lane ^= 1 swap, pure-VALU
__device__ __forceinline__ float dpp_xor1(float x) {
    return __int_as_float(__builtin_amdgcn_update_dpp(
        0, __float_as_int(x), 0xB1, 0xF, 0xF, true));
}
// d = 1 + exp2(k*z), componentwise exp2 (trans is scalar-only; mul/add pack)
__device__ __forceinline__ f32x2 dexp2(f32x2 z, float k) {
    f32x2 t = z * k;
    f32x2 e;
    e.x = __builtin_amdgcn_exp2f(t.x);
    e.y = __builtin_amdgcn_exp2f(t.y);
    return e + 1.0f;
}
// elementwise recip of 4 independent denoms with 2 rcp + 3 pk_mul (vs 4 rcp)
__device__ __forceinline__ void brcp4(f32x2 d01, f32x2 d23, f32x2& s01, f32x2& s23) {
    const f32x2 m = d01 * d23;
    f32x2 R;
    R.x = __builtin_amdgcn_rcpf(m.x);
    R.y = __builtin_amdgcn_rcpf(m.y);
    s01 = R * d23;
    s23 = R * d01;
}

__device__ __forceinline__ unsigned short f2bf(float a) {
    unsigned int u = __float_as_uint(a);
    u += 0x7FFFu + ((u >> 16) & 1u);
    return (unsigned short)(u >> 16);
}
__device__ __forceinline__ unsigned int pack2bf(float a, float b) {
    unsigned int ua = __float_as_uint(a); ua += 0x7FFFu + ((ua >> 16) & 1u);
    unsigned int ub = __float_as_uint(b); ub += 0x7FFFu + ((ub >> 16) & 1u);
    return (ua >> 16) | (ub & 0xFFFF0000u);
}
union frag_u { short8 v; unsigned int u[4]; };
union h2x  { unsigned int u32; _Float16 h[2]; };

// FUSED producer-consumer kernel: 1 block/sequence, 512 threads (8 waves).
// R16 theory: phase-2 step is DEPENDENCY-LATENCY bound (~20 serial ops);
// issue slots are idle (R2's issue cuts = 0, R1/R3's latency cuts paid).
// Chain -5 dependent ops:
//  * weights & P pre-scaled by the exp2 constants (kills z*k pk_mul)
//  * cell state kept pre-scaled (cs = KTANH*c; gate-finish fma emits
//    KTANH*tanh(z_g) directly) -- kills the K*c mul
//  * dpp BOTH gate words right after the finish-fma so even lanes compute
//    c, tanh(c), h locally -- kills the second dpp; h lives on EVEN lanes
//  * matvec as 8 chains x depth 3 + depth-3 tree (was 4x6 + depth 2)
// Also: producer worklists rebalanced (w7:{7,14,15}); producer acc-init
// packed f32x2; consumer prio 3.
__global__ __attribute__((amdgpu_flat_work_group_size(512, 512)))
__attribute__((amdgpu_waves_per_eu(2, 2)))
void fused_kernel(
    const float* __restrict__ x,        // [B*T*S]
    const int*   __restrict__ lengths,  // [B]
    const float* __restrict__ Wi,       // [G1]
    const float* __restrict__ Ui,       // [U1*G1]
    const float* __restrict__ bi,       // [G1]
    const float* __restrict__ Wo,       // [U1*G2]
    const float* __restrict__ Uo,       // [U2*G2]
    const float* __restrict__ bo,       // [G2]
    const float* __restrict__ Wd,       // [U2]
    const float* __restrict__ bd,       // [1]
    float* __restrict__ out)            // [B]
{
    __shared__ __align__(16) _Float16      Pl[T_][G2];      // [t][u*4+g], 48 KB
    __shared__ __align__(16) unsigned short hbb[8][16][40]; // per-wave h tiles
    __shared__ unsigned int flags[NT];
    const int b    = blockIdx.x;
    const int len  = lengths[b];                 // >= 1
    const int tid  = threadIdx.x;
    const int w    = __builtin_amdgcn_readfirstlane(tid >> 6);   // wave 0..7
    const int lane = tid & 63;
    const int q    = lane >> 4;
    const int n    = lane & 15;

    if (tid < NT) flags[tid] = 0;
    __syncthreads();                             // only barrier: flag init

    // priority: waves 0-3 produce tiles 0-3 (the consumer's first needs) at
    // prio 2; dropped after first tile (wave0 -> 3 = consumer wins always).
    if (w <= 3) __builtin_amdgcn_s_setprio(2);

    // ---- one-time fragment/bias loads (all waves produce) ----
    frag_u Bui[8];
#pragma unroll
    for (int tt = 0; tt < 8; ++tt)
#pragma unroll
        for (int k2 = 0; k2 < 4; ++k2)
            Bui[tt].u[k2] = pack2bf(Ui[(8 * q + 2 * k2) * G1 + 16 * tt + n],
                                    Ui[(8 * q + 2 * k2 + 1) * G1 + 16 * tt + n]);
    frag_u Bwo[6];
#pragma unroll
    for (int tt = 0; tt < 6; ++tt)
#pragma unroll
        for (int k2 = 0; k2 < 4; ++k2)
            Bwo[tt].u[k2] = pack2bf(Wo[(8 * q + 2 * k2) * G2 + 16 * tt + n],
                                    Wo[(8 * q + 2 * k2 + 1) * G2 + 16 * tt + n]);
    float bi_l[8], Wi_l[8], bo_l[6];
#pragma unroll
    for (int tt = 0; tt < 8; ++tt) { bi_l[tt] = bi[16 * tt + n]; Wi_l[tt] = Wi[16 * tt + n]; }
#pragma unroll
    for (int tt = 0; tt < 6; ++tt) bo_l[tt] = bo[16 * tt + n];
    // P-store targets: col=16tt+n -> (g=col/24, u=col%24) -> offset u*4+g
    int pcol[6];
#pragma unroll
    for (int tt = 0; tt < 6; ++tt) {
        const int col = 16 * tt + n;
        const int g = col / 24;
        pcol[tt] = (col - 24 * g) * 4 + g;
    }

    // ---- tile worklist: wave0 gets only tile 0; balanced second pass so no
    //      wave owns 3 early-needed tiles (w7's extras are needed last).
    int tl[3]; int ntl;
    if (w == 0)      { tl[0] = 0; tl[1] = 0;  tl[2] = 0;  ntl = 1; }
    else if (w == 7) { tl[0] = 7; tl[1] = 14; tl[2] = 15; ntl = 3; }
    else             { tl[0] = w; tl[1] = w + 7; tl[2] = 0; ntl = 2; }

#pragma unroll 1
    for (int i = 0; i < ntl; ++i) {
        const int tile = tl[i];
        const int wt0  = tile * 16;
        if (wt0 >= len) break;                   // lists increasing: later also masked

        const float* xr = x + (size_t)(b * T_ + wt0 + 4 * q) * S_;
        // cell state as row-pair packs: c01 = rows (4q+0,4q+1), c23 = (+2,+3)
        f32x2 c01[2], c23[2];
#pragma unroll
        for (int uh = 0; uh < 2; ++uh) { c01[uh] = {0.0f, 0.0f}; c23[uh] = {0.0f, 0.0f}; }

        // packed activation block: 60 trans ops/step, pk elsewhere
        auto activate = [&](f32x4* acc) {
#pragma unroll
            for (int uh = 0; uh < 2; ++uh) {
                const f32x2 zi01 = { acc[0 + uh][0], acc[0 + uh][1] };
                const f32x2 zi23 = { acc[0 + uh][2], acc[0 + uh][3] };
                const f32x2 zf01 = { acc[2 + uh][0], acc[2 + uh][1] };
                const f32x2 zf23 = { acc[2 + uh][2], acc[2 + uh][3] };
                const f32x2 zg01 = { acc[4 + uh][0], acc[4 + uh][1] };
                const f32x2 zg23 = { acc[4 + uh][2], acc[4 + uh][3] };
                const f32x2 zo01 = { acc[6 + uh][0], acc[6 + uh][1] };
                const f32x2 zo23 = { acc[6 + uh][2], acc[6 + uh][3] };

                f32x2 si01, si23, sf01, sf23, rg01, rg23, so01, so23;
                brcp4(dexp2(zi01, KSIG),  dexp2(zi23, KSIG),  si01, si23);
                brcp4(dexp2(zf01, KSIG),  dexp2(zf23, KSIG),  sf01, sf23);
                brcp4(dexp2(zg01, KTANH), dexp2(zg23, KTANH), rg01, rg23);
                brcp4(dexp2(zo01, KSIG),  dexp2(zo23, KSIG),  so01, so23);
                const f32x2 g01 = 1.0f - 2.0f * rg01;
                const f32x2 g23 = 1.0f - 2.0f * rg23;
                c01[uh] = sf01 * c01[uh] + si01 * g01;
                c23[uh] = sf23 * c23[uh] + si23 * g23;
                f32x2 rc01, rc23;
                brcp4(dexp2(c01[uh], KTANH), dexp2(c23[uh], KTANH), rc01, rc23);
                const f32x2 t01 = 1.0f - 2.0f * rc01;
                const f32x2 t23 = 1.0f - 2.0f * rc23;
                const f32x2 h01 = so01 * t01;
                const f32x2 h23 = so23 * t23;
                hbb[w][4 * q + 0][n + 16 * uh] = f2bf(h01.x);
                hbb[w][4 * q + 1][n + 16 * uh] = f2bf(h01.y);
                hbb[w][4 * q + 2][n + 16 * uh] = f2bf(h23.x);
                hbb[w][4 * q + 3][n + 16 * uh] = f2bf(h23.y);
            }
        };

        float xc[4];
#pragma unroll
        for (int r = 0; r < 4; ++r) xc[r] = xr[r * S_];

        // peeled s = 0 (h == 0: no MFMA)
        {
            const f32x2 xc01 = { xc[0], xc[1] }, xc23 = { xc[2], xc[3] };
            f32x4 acc[8];
#pragma unroll
            for (int tt = 0; tt < 8; ++tt) {
                const f32x2 a01 = xc01 * Wi_l[tt] + bi_l[tt];
                const f32x2 a23 = xc23 * Wi_l[tt] + bi_l[tt];
                acc[tt][0] = a01.x; acc[tt][1] = a01.y;
                acc[tt][2] = a23.x; acc[tt][3] = a23.y;
            }
            activate(acc);
        }
#pragma unroll
        for (int r = 0; r < 4; ++r) xc[r] = xr[r * S_ + 1];

        // steady state s = 1..19
#pragma unroll 1
        for (int s = 1; s < S_; ++s) {
            const int sn = (s + 1 < S_) ? s + 1 : S_ - 1;
            float xnx[4];
#pragma unroll
            for (int r = 0; r < 4; ++r) xnx[r] = xr[r * S_ + sn];

            const f32x2 xc01 = { xc[0], xc[1] }, xc23 = { xc[2], xc[3] };
            f32x4 acc[8];
#pragma unroll
            for (int tt = 0; tt < 8; ++tt) {
                const f32x2 a01 = xc01 * Wi_l[tt] + bi_l[tt];
                const f32x2 a23 = xc23 * Wi_l[tt] + bi_l[tt];
                acc[tt][0] = a01.x; acc[tt][1] = a01.y;
                acc[tt][2] = a23.x; acc[tt][3] = a23.y;
            }

            const short8 A = *(const short8*)&hbb[w][n][8 * q];
#pragma unroll
            for (int tt = 0; tt < 8; ++tt)
                acc[tt] = __builtin_amdgcn_mfma_f32_16x16x32_bf16(A, Bui[tt].v, acc[tt], 0, 0, 0);

            activate(acc);
#pragma unroll
            for (int r = 0; r < 4; ++r) xc[r] = xnx[r];
        }

        // P tile = bo + h @ Wo -> LDS, unit-major pair layout
        {
            const short8 A = *(const short8*)&hbb[w][n][8 * q];
            f32x4 accp[6];
#pragma unroll
            for (int tt = 0; tt < 6; ++tt) {
#pragma unroll
                for (int r = 0; r < 4; ++r) accp[tt][r] = bo_l[tt];
                accp[tt] = __builtin_amdgcn_mfma_f32_16x16x32_bf16(A, Bwo[tt].v, accp[tt], 0, 0, 0);
            }
#pragma unroll
            for (int r = 0; r < 4; ++r) {
                const int tr = wt0 + 4 * q + r;
#pragma unroll
                for (int tt = 0; tt < 6; ++tt)
                    Pl[tr][pcol[tt]] = (_Float16)accp[tt][r];
            }
        }
        // release this tile to the consumer (DS ops in-order; release fences)
        __hip_atomic_store(&flags[tile], 1u, __ATOMIC_RELEASE, __HIP_MEMORY_SCOPE_WORKGROUP);
        if (i == 0) {
            if (w == 0) __builtin_amdgcn_s_setprio(3);   // consumer priority
            else        __builtin_amdgcn_s_setprio(0);   // back to baseline
        }
    }

    if (w != 0) return;                          // producers retire

    // ================= phase 2: outer LSTM + head (wave 0) =================
    // Parity pipeline, chain-minimized:
    //   even lane 2u: z=(zi,zf) prescaled by KSIG; odd 2u+1: (zg,zo) by
    //   (KTANH,KSIG). Gate-finish fma gives (si,sf) on even and
    //   (KTANH*tanh(zg), so) on odd. Both words dpp'd: even lanes then hold
    //   all four gates and carry cs = KTANH*c, tc, hu LOCALLY (no 2nd dpp).
    const int p = lane & 1;                      // 0: i,f  1: g,o
    const int u = (lane < 2 * U2) ? (lane >> 1) : (U2 - 1);
    const int cA = p ? (2 * U2 + u) : u;         // col of zA dot
    const int cB = p ? (3 * U2 + u) : (U2 + u);  // col of zB dot

    const float kx = p ? KTANH : KSIG;
    const f32x2 kv  = { kx, KSIG };                        // P prescale
    const f32x2 mAB = { p ? (-2.0f * KTANH) : 1.0f, 1.0f };
    const f32x2 aAB = { p ? KTANH : 0.0f, 0.0f };

    f32x2 w2_[U2];                               // prescaled weight pairs
#pragma unroll
    for (int k = 0; k < U2; ++k) {
        w2_[k].x = Uo[k * G2 + cA] * kx;
        w2_[k].y = Uo[k * G2 + cB] * KSIG;
    }

    // row word -> prescaled f32 pair (off the hu-chain; scheduled early)
    auto cvt2 = [&](unsigned rw) -> f32x2 {
        h2x s_; s_.u32 = rw;
        f32x2 r; r.x = (float)s_.h[0]; r.y = (float)s_.h[1];
        return r * kv;
    };

    // per-lane byte offset within a P row: the parity select is folded into
    // the address -> a single ds_read_b32 fetches exactly this lane's pair.
    const int rowoff = 8 * u + 4 * p;            // bytes; row stride 192 B
    const char* Pb = reinterpret_cast<const char*>(&Pl[0][0]);
    const int ntiles = (len + 15) >> 4;

    unsigned bufA[16], bufB[16];                 // double-buffered row regs

    float cs = 0.0f, hu = 0.0f;                  // cs,hu valid on EVEN lanes

// one recurrence step from a register-held row.
// chain: readlane -> 3xfma -> 3xadd -> exp2 -> add -> rcp -> fma -> dpp ->
//        mul -> fma(cs) -> exp2 -> add -> rcp -> fma -> mul(hu)
#define STEP_ROW(RW) do {                                                     \
    const f32x2 pr = cvt2(RW);                                                \
    float hk[U2];                                                             \
    _Pragma("unroll")                                                         \
    for (int kq = 0; kq < U2; ++kq)                                           \
        hk[kq] = __int_as_float(                                              \
            __builtin_amdgcn_readlane(__float_as_int(hu), 2 * kq));           \
    f32x2 ab0 = pr;                                                           \
    f32x2 ab1 = {0.f,0.f}, ab2 = {0.f,0.f}, ab3 = {0.f,0.f};                  \
    f32x2 ab4 = {0.f,0.f}, ab5 = {0.f,0.f}, ab6 = {0.f,0.f}, ab7 = {0.f,0.f}; \
    _Pragma("unroll")                                                         \
    for (int mq = 0; mq < 3; ++mq) {                                          \
        ab0 += w2_[8 * mq + 0] * hk[8 * mq + 0];                              \
        ab1 += w2_[8 * mq + 1] * hk[8 * mq + 1];                              \
        ab2 += w2_[8 * mq + 2] * hk[8 * mq + 2];                              \
        ab3 += w2_[8 * mq + 3] * hk[8 * mq + 3];                              \
        ab4 += w2_[8 * mq + 4] * hk[8 * mq + 4];                              \
        ab5 += w2_[8 * mq + 5] * hk[8 * mq + 5];                              \
        ab6 += w2_[8 * mq + 6] * hk[8 * mq + 6];                              \
        ab7 += w2_[8 * mq + 7] * hk[8 * mq + 7];                              \
    }                                                                         \
    const f32x2 zz = (((ab0 + ab1) + (ab2 + ab3)) +                           \
                      ((ab4 + ab5) + (ab6 + ab7)));                           \
    f32x2 e_;                                                                 \
    e_.x = __builtin_amdgcn_exp2f(zz.x);                                      \
    e_.y = __builtin_amdgcn_exp2f(zz.y);                                      \
    const f32x2 d_ = e_ + 1.0f;                                               \
    f32x2 r_;                                                                 \
    r_.x = __builtin_amdgcn_rcpf(d_.x);                                       \
    r_.y = __builtin_amdgcn_rcpf(d_.y);                                       \
    const f32x2 o2 = r_ * mAB + aAB;                                          \
    const float swx = dpp_xor1(o2.x);            /* even <- K*tanh(zg) */     \
    const float swy = dpp_xor1(o2.y);            /* even <- so        */      \
    cs = o2.y * cs + o2.x * swx;                 /* even: sf*cs + si*Ktg */   \
    const float e2 = __builtin_amdgcn_exp2f(cs);                              \
    const float r2 = __builtin_amdgcn_rcpf(1.0f + e2);                        \
    const float tc = 1.0f - 2.0f * r2;           /* tanh(c) on even */        \
    hu = swy * tc;                               /* even: so*tanh(c) */       \
} while (0)

// consume tile K from CUR; mid-tile, spin + issue next tile's reads into NXT
// (their lgkmcnt wait lands at the next tile's first use -> latency hidden)
#define TILE_BODY(K, CUR, NXT, J0) do {                                       \
    _Pragma("unroll")                                                         \
    for (int j = (J0); j < 8; ++j) {                                          \
        if (16 * (K) + j >= len) goto p2done;                                 \
        STEP_ROW(CUR[j]);                                                     \
    }                                                                         \
    if ((K) + 1 < ntiles) {                                                   \
        while (__hip_atomic_load(&flags[(K) + 1], __ATOMIC_ACQUIRE,           \
                                 __HIP_MEMORY_SCOPE_WORKGROUP) == 0u)         \
            __builtin_amdgcn_s_sleep(1);                                      \
        _Pragma("unroll")                                                     \
        for (int j = 0; j < 16; ++j)                                          \
            NXT[j] = *reinterpret_cast<const unsigned*>(                      \
                Pb + (16 * ((K) + 1) + j) * (G2 * 2) + rowoff);               \
    }                                                                         \
    _Pragma("unroll")                                                         \
    for (int j = 8; j < 16; ++j) {                                            \
        if (16 * (K) + j >= len) goto p2done;                                 \
        STEP_ROW(CUR[j]);                                                     \
    }                                                                         \
} while (0)

    // tile 0: produced by this wave itself (own DS writes are in-order)
#pragma unroll
    for (int j = 0; j < 16; ++j)
        bufA[j] = *reinterpret_cast<const unsigned*>(Pb + j * (G2 * 2) + rowoff);

    {   // peeled t = 0 (h == 0, c == 0): z = P row 0 (prescaled)
        const f32x2 z0 = cvt2(bufA[0]);
        f32x2 e_;
        e_.x = __builtin_amdgcn_exp2f(z0.x);
        e_.y = __builtin_amdgcn_exp2f(z0.y);
        const f32x2 d_ = e_ + 1.0f;
        f32x2 r_;
        r_.x = __builtin_amdgcn_rcpf(d_.x);
        r_.y = __builtin_amdgcn_rcpf(d_.y);
        const f32x2 o2 = r_ * mAB + aAB;
        const float swx = dpp_xor1(o2.x);
        const float swy = dpp_xor1(o2.y);
        cs = o2.x * swx;                         // even: si * Ktg (c_prev=0)
        const float e2 = __builtin_amdgcn_exp2f(cs);
        const float r2 = __builtin_amdgcn_rcpf(1.0f + e2);
        const float tc = 1.0f - 2.0f * r2;
        hu = swy * tc;
    }

    TILE_BODY(0, bufA, bufB, 1);
#pragma unroll 1
    for (int k = 1; k < ntiles; ++k) {
        if (k & 1) TILE_BODY(k, bufB, bufA, 0);
        else       TILE_BODY(k, bufA, bufB, 0);
    }
p2done: ;

    // dense sigmoid head (h on even lanes)
    float acc = bd[0];
#pragma unroll
    for (int k = 0; k < U2; ++k)
        acc += __int_as_float(__builtin_amdgcn_readlane(__float_as_int(hu), 2 * k)) * Wd[k];
    if (lane == 0) out[b] = sigmoidf_(acc);

#undef TILE_BODY
#undef STEP_ROW
}

extern "C" void kernel_launch(void* const* d_in, const int* in_sizes, int n_in,
                              void* d_out, int out_size, void* d_ws, size_t ws_size,
                              hipStream_t stream) {
    const float* x       = (const float*)d_in[0];
    const int*   lengths = (const int*)  d_in[1];
    const float* Wi      = (const float*)d_in[2];
    const float* Ui      = (const float*)d_in[3];
    const float* bi      = (const float*)d_in[4];
    const float* Wo      = (const float*)d_in[5];
    const float* Uo      = (const float*)d_in[6];
    const float* bo      = (const float*)d_in[7];
    const float* Wd      = (const float*)d_in[8];
    const float* bd      = (const float*)d_in[9];
    float* out = (float*)d_out;

    fused_kernel<<<dim3(B_), dim3(512), 0, stream>>>(
        x, lengths, Wi, Ui, bi, Wo, Uo, bo, Wd, bd, out);
}